// Round 2
// baseline (2737.764 us; speedup 1.0000x reference)
//
#include <hip/hip_runtime.h>

typedef unsigned short u16;
typedef unsigned int u32;
typedef unsigned long long u64;
typedef short v8s __attribute__((ext_vector_type(8)));
typedef float v4f __attribute__((ext_vector_type(4)));

// Dims: B=256, T=512, D=32, H=256, 4H=1024, A=128, HOR=24, NQ=3
// 256 blocks = 16 groups (16 batch rows) x 16 slices (16 units = 64 gate-cols).
// Cross-block exchange: tagged payload + per-writer SENTINEL word. Readers poll
// ONLY the 16-sentinel line (1 coalesced 64B request/wave/round) instead of the
// 16KB payload -> no L2 poll flood. Payload bulk-loaded once after sentinel,
// embedded tags verified (race -> one reload). LDS layouts = round-0 (measured
// fewer bank conflicts than swizzled variants).

__device__ __forceinline__ float bf2f(u16 u) { union { u32 u; float f; } c; c.u = ((u32)u) << 16; return c.f; }
__device__ __forceinline__ u16 f2bf(float f) {
  union { float f; u32 u; } c; c.f = f;
  u32 r = c.u + 0x7FFFu + ((c.u >> 16) & 1u);   // RTNE
  return (u16)(r >> 16);
}
__device__ __forceinline__ float sigf(float x) { return 1.f / (1.f + __expf(-x)); }
__device__ __forceinline__ float tanhfast(float x) {
  x = fminf(15.f, fmaxf(-15.f, x));
  float e = __expf(2.f * x);
  return (e - 1.f) / (e + 1.f);
}
__device__ __forceinline__ float ldIn(const void* p, size_t i, int isbf) {
  return isbf ? bf2f(((const u16*)p)[i]) : ((const float*)p)[i];
}
__device__ __forceinline__ v8s ld8hi(const void* p, size_t e, int isbf) {
  if (isbf) return *(const v8s*)((const u16*)p + e);
  const float* f = (const float*)p + e;
  v8s r;
#pragma unroll
  for (int j = 0; j < 8; ++j) r[j] = (short)f2bf(f[j]);
  return r;
}
__device__ __forceinline__ void ld8split(const void* p, size_t e, int isbf, v8s& hi, v8s& lo) {
  if (isbf) {
    hi = *(const v8s*)((const u16*)p + e);
    lo = v8s{0, 0, 0, 0, 0, 0, 0, 0};
  } else {
    const float* f = (const float*)p + e;
#pragma unroll
    for (int j = 0; j < 8; ++j) {
      u16 h = f2bf(f[j]);
      hi[j] = (short)h;
      lo[j] = (short)f2bf(f[j] - bf2f(h));
    }
  }
}
#define MFMA(a, b, c) __builtin_amdgcn_mfma_f32_16x16x32_bf16(a, b, c, 0, 0, 0)

__device__ __forceinline__ u64 aload64(const u64* p) {
  return __hip_atomic_load(p, __ATOMIC_RELAXED, __HIP_MEMORY_SCOPE_AGENT);
}
__device__ __forceinline__ u32 aload32(const u32* p) {
  return __hip_atomic_load(p, __ATOMIC_RELAXED, __HIP_MEMORY_SCOPE_AGENT);
}
__device__ __forceinline__ void astore32(u32* p, u32 v) {
  __hip_atomic_store(p, v, __ATOMIC_RELAXED, __HIP_MEMORY_SCOPE_AGENT);
}
__device__ __forceinline__ void astore64(u64* p, u64 v) {
  __hip_atomic_store(p, v, __ATOMIC_RELAXED, __HIP_MEMORY_SCOPE_AGENT);
}

// ---- sentinel poll: each lane watches sentinel[lane&15]; exit when all >= tag.
// One coalesced 64B L2 request per wave per round (vs 16KB payload spin).
__device__ __forceinline__ void poll16(const u32* tl, int lane, u32 tag) {
  u32 s = aload32(tl + (lane & 15));
  while (!__all(s >= tag)) s = aload32(tl + (lane & 15));
}
// ---- payload bulk load (once, after sentinel)
__device__ __forceinline__ void load8(u64* v, const u32* src, int tid) {
  const u64* p = (const u64*)src;
#pragma unroll
  for (int i = 0; i < 8; ++i) v[i] = aload64(p + i * 256 + tid);
}
// ---- verify embedded tags (sentinel race -> at most one reload), unpack to LDS.
// Payload layout per parity: [gs(16)][row(16)][8 u64] (writer-exclusive 1KB runs),
// word = bf16lo | tag<<16 per unit. LDS: [row][264 u16], u32 col = gs*8 + c.
__device__ __forceinline__ void verify_unpack(u16* dst, const u32* src, u64* v,
                                              int tid, u32 tag) {
  const u64* p = (const u64*)src;
  bool all;
  do {
    all = true;
#pragma unroll
    for (int i = 0; i < 8; ++i) {
      u64 w = v[i];
      if (!((((w >> 16) & 0xFFFFull) == tag) && ((w >> 48) == tag))) {
        all = false;
        v[i] = aload64(p + i * 256 + tid);
      }
    }
  } while (!all);
#pragma unroll
  for (int i = 0; i < 8; ++i) {
    int idx = i * 256 + tid;
    int gs2 = idx >> 7, row = (idx >> 3) & 15, c = idx & 7;
    u64 w = v[i];
    ((u32*)(dst + row * 264))[gs2 * 8 + c] =
        (u32)(w & 0xFFFF) | ((((u32)(w >> 32)) & 0xFFFF) << 16);
  }
}

// ---- Decoder tagged stage (unchanged): u64/unit = hi | lo<<16 | tag<<32, [16][256] u64.
__device__ __forceinline__ void stage_dec(u16* dhi, u16* dlo, const u64* src,
                                          int tid, u32 tag) {
  u64 v[16];
#pragma unroll
  for (int i = 0; i < 16; ++i) v[i] = aload64(src + i * 256 + tid);
  bool all;
  do {
    all = true;
#pragma unroll
    for (int i = 0; i < 16; ++i) {
      if ((u32)(v[i] >> 32) != tag) { all = false; v[i] = aload64(src + i * 256 + tid); }
    }
  } while (!all);
#pragma unroll
  for (int i = 0; i < 16; ++i) {
    int idx = i * 256 + tid;
    int row = idx >> 8, col = idx & 255;
    dhi[row * 264 + col] = (u16)v[i];
    dlo[row * 264 + col] = (u16)(v[i] >> 16);
  }
}
__device__ __forceinline__ void stage_f32(u16* dhi, u16* dlo, const float* src, int tid) {
#pragma unroll
  for (int i = 0; i < 8; ++i) {
    int e = i * 512 + tid * 2;
    int row = e >> 8, jc = e & 255;
    float f0 = src[row * 256 + jc], f1 = src[row * 256 + jc + 1];
    u16 h0 = f2bf(f0), h1 = f2bf(f1);
    u16 l0 = f2bf(f0 - bf2f(h0)), l1 = f2bf(f1 - bf2f(h1));
    ((u32*)(dhi + row * 264))[jc >> 1] = (u32)h0 | ((u32)h1 << 16);
    ((u32*)(dlo + row * 264))[jc >> 1] = (u32)l0 | ((u32)l1 << 16);
  }
}

__global__ void sniff_kernel(const u16* __restrict__ w, int* __restrict__ flag) {
  __shared__ int cnt;
  if (threadIdx.x == 0) cnt = 0;
  __syncthreads();
  int ok = 0;
  for (int i = threadIdx.x; i < 1024; i += 256) {
    u16 u = w[2 * i];
    int e = (u >> 7) & 0xFF;
    ok += (u == 0 || (e >= 97 && e <= 140)) ? 1 : 0;
  }
  atomicAdd(&cnt, ok);
  __syncthreads();
  if (threadIdx.x == 0) *flag = (cnt >= 768) ? 1 : 0;
}

// ---------------- Encoder (both LSTM layers, pipelined) + fused online attention ---
__global__ __launch_bounds__(256, 1) void enc_kernel(
    const void* __restrict__ x,
    const void* __restrict__ eWih0, const void* __restrict__ eWhh0, const void* __restrict__ eb0,
    const void* __restrict__ eWih1, const void* __restrict__ eWhh1, const void* __restrict__ eb1,
    const void* __restrict__ aW, const void* __restrict__ aV,
    u32* __restrict__ H0, u32* __restrict__ H1,
    u32* __restrict__ H0tag, u32* __restrict__ H1tag,
    float* __restrict__ ctx, const int* __restrict__ flagp) {
  __shared__ __align__(16) u16 h0s[16 * 264], h1s[16 * 264];
  __shared__ float gb0[16 * 64], gb1[16 * 64];
  __shared__ float eP[16 * 132];

  const int isbf = *flagp;
  const int tid = threadIdx.x, blk = blockIdx.x;
  const int grp = blk & 15, gs = blk >> 4;
  const int lane = tid & 63, wv = tid >> 6;      // wave = gate index
  const int ln = lane & 15, lq = lane >> 4;

  v8s W0F[9], W1F[16], AWF[16];
  {
    const int gw = wv * 256 + gs * 16 + ln;
    const int kq = lq * 8;
    W0F[0] = ld8hi(eWih0, (size_t)gw * 32 + kq, isbf);
#pragma unroll
    for (int kt = 0; kt < 8; ++kt) {
      W0F[kt + 1] = ld8hi(eWhh0, (size_t)gw * 256 + kt * 32 + kq, isbf);
      W1F[kt]     = ld8hi(eWhh1, (size_t)gw * 256 + kt * 32 + kq, isbf);
      W1F[kt + 8] = ld8hi(eWih1, (size_t)gw * 256 + kt * 32 + kq, isbf);
    }
#pragma unroll
    for (int kt = 0; kt < 8; ++kt)
#pragma unroll
      for (int j2 = 0; j2 < 2; ++j2) {
        v8s f;
        int ac = (2 * wv + j2) * 16 + ln;
#pragma unroll
        for (int j = 0; j < 8; ++j)
          f[j] = (short)f2bf(ldIn(aW, (size_t)(kt * 32 + kq + j) * 128 + ac, isbf));
        AWF[kt * 2 + j2] = f;
      }
  }

  const int urow = tid >> 4, uu = tid & 15;
  float bg0[4], bg1[4], aVr[8];
#pragma unroll
  for (int g = 0; g < 4; ++g) {
    bg0[g] = ldIn(eb0, g * 256 + gs * 16 + uu, isbf);
    bg1[g] = ldIn(eb1, g * 256 + gs * 16 + uu, isbf);
  }
#pragma unroll
  for (int j = 0; j < 8; ++j) aVr[j] = ldIn(aV, (size_t)(uu + 16 * j), isbf);

  const int gRowU = grp * 16 + urow;
  const int gUnit = gs * 16 + uu;
  const int aRow = grp * 16 + ln;
  // writer-exclusive store slot (1KB contiguous per block, full 128B lines)
  const u32 stOff = (u32)(grp * 4096 + gs * 256 + urow * 16 + uu);
  const u32* tl0 = H0tag + grp * 32;   // 16 sentinels (one 64B span) per grp
  const u32* tl1 = H1tag + grp * 32;

  float c0 = 0.f, c1 = 0.f;
  float mS = -3e38f, lS = 0.f, ctxA = 0.f;

  v8s xh_c, xl_c;
  ld8split(x, ((size_t)aRow * 512) * 32 + lq * 8, isbf, xh_c, xl_c);
  v8s a0r[8];

  // t: L0 -> h0[t]; L1 -> h1[t-1]; attn+ctx consume h1[t-2]
#pragma unroll 1
  for (int t = 0; t < 514; ++t) {
    const int rB = (t + 1) & 1, wB = t & 1;
    const u32 tag = (u32)(u16)t;
    // ---- S1: sentinel-poll h0[t-1], bulk load, verify, unpack
    if (t <= 512) {
      const u32* src0 = H0 + (size_t)rB * 65536 + grp * 4096;
      poll16(tl0, lane, (u32)t);
      u64 v0[8];
      load8(v0, src0, tid);
      verify_unpack(h0s, src0, v0, tid, tag);
    }
    __syncthreads();                                   // b1: h0s ready

    // ---- P1: publish h1 sentinel (payload drained by b1's vmcnt); L0 MFMAs
    if (t >= 1 && tid == 0) astore32(H1tag + grp * 32 + gs, (u32)t);
    if (t <= 512) {
#pragma unroll
      for (int kt = 0; kt < 8; ++kt)
        a0r[kt] = *(const v8s*)(h0s + ln * 264 + kt * 32 + lq * 8);
    }
    if (t < 512) {
      v4f acc0 = {0, 0, 0, 0};
      acc0 = MFMA(xh_c, W0F[0], acc0);
      if (!isbf) acc0 = MFMA(xl_c, W0F[0], acc0);
#pragma unroll
      for (int kt = 0; kt < 8; ++kt) acc0 = MFMA(a0r[kt], W0F[kt + 1], acc0);
#pragma unroll
      for (int r = 0; r < 4; ++r) gb0[(lq * 4 + r) * 64 + ln * 4 + wv] = acc0[r];
    }
    __syncthreads();                                   // b2: gb0 ready

    // ---- P2: poll h1 sentinel + issue payload loads; cell0 + h0 store overlap
    const u32* src1 = H1 + (size_t)wB * 65536 + grp * 4096;
    poll16(tl1, lane, (u32)t);
    u64 v1[8];
    load8(v1, src1, tid);
    const u32 tagS = (u32)(u16)(t + 1) << 16;
    if (t < 512) {
      const float* g0 = gb0 + (urow * 16 + uu) * 4;
      float gi = g0[0] + bg0[0], gf = g0[1] + bg0[1], gg = g0[2] + bg0[2], go = g0[3] + bg0[3];
      c0 = sigf(gf) * c0 + sigf(gi) * tanhfast(gg);
      float h = sigf(go) * tanhfast(c0);
      astore32(H0 + (size_t)wB * 65536 + stOff, (u32)f2bf(h) | tagS);
    }
    verify_unpack(h1s, src1, v1, tid, tag);
    float h1v = bf2f(h1s[urow * 264 + gUnit]);   // for attn ctx (h1s stable after)
    __syncthreads();                                   // b3: h1s ready, h0 stores drained

    // ---- P3: publish h0 sentinel FIRST; then L1 + attention MFMAs
    if (t < 512 && tid == 0) astore32(H0tag + grp * 32 + gs, (u32)(t + 1));
    v4f acc1 = {0, 0, 0, 0}, accA0 = {0, 0, 0, 0}, accA1 = {0, 0, 0, 0};
#pragma unroll
    for (int kt = 0; kt < 8; ++kt) {
      v8s a1 = *(const v8s*)(h1s + ln * 264 + kt * 32 + lq * 8);
      acc1 = MFMA(a0r[kt], W1F[kt + 8], acc1);
      acc1 = MFMA(a1, W1F[kt], acc1);
      accA0 = MFMA(a1, AWF[kt * 2], accA0);
      accA1 = MFMA(a1, AWF[kt * 2 + 1], accA1);
    }
#pragma unroll
    for (int r = 0; r < 4; ++r) {
      gb1[(lq * 4 + r) * 64 + ln * 4 + wv] = acc1[r];
      eP[(lq * 4 + r) * 132 + (2 * wv) * 16 + ln] = accA0[r];
      eP[(lq * 4 + r) * 132 + (2 * wv + 1) * 16 + ln] = accA1[r];
    }
    // x prefetch for t+1 (off the h0 critical path)
    v8s xh_n, xl_n;
    {
      int tn = (t + 1 < 512) ? t + 1 : 511;
      ld8split(x, ((size_t)aRow * 512 + tn) * 32 + lq * 8, isbf, xh_n, xl_n);
    }
    __syncthreads();                                   // b4: gb1/eP ready

    // ---- P4: cell1 + store h1[t-1]; attention tail
    if (t >= 1 && t < 513) {
      const float* g1 = gb1 + (urow * 16 + uu) * 4;
      float gi = g1[0] + bg1[0], gf = g1[1] + bg1[1], gg = g1[2] + bg1[2], go = g1[3] + bg1[3];
      c1 = sigf(gf) * c1 + sigf(gi) * tanhfast(gg);
      float h = sigf(go) * tanhfast(c1);
      astore32(H1 + (size_t)rB * 65536 + stOff, (u32)f2bf(h) | tagS);
    } else if (t == 0) {
      astore32(H1 + (size_t)rB * 65536 + stOff, tagS);  // h1[-1]=0, tag 1
    }
    if (t >= 2) {
      float e = 0.f;
#pragma unroll
      for (int j = 0; j < 8; ++j)
        e += tanhfast(eP[urow * 132 + uu + 16 * j]) * aVr[j];
      e += __shfl_xor(e, 1);
      e += __shfl_xor(e, 2);
      e += __shfl_xor(e, 4);
      e += __shfl_xor(e, 8);
      float nm = fmaxf(mS, e);
      float al = __expf(mS - nm), p = __expf(e - nm);
      lS = lS * al + p;
      ctxA = ctxA * al + p * h1v;
      mS = nm;
    }
    xh_c = xh_n; xl_c = xl_n;
  }
  ctx[(size_t)gRowU * 256 + gUnit] = ctxA / lS;
}

// ---------------- Decoder: 24 steps x 2 sub-steps + projection (hi/lo, tagged u64) -
__global__ __launch_bounds__(256, 1) void dec_kernel(
    const void* __restrict__ x,
    const void* __restrict__ dWih0, const void* __restrict__ dWhh0, const void* __restrict__ db0,
    const void* __restrict__ dWih1, const void* __restrict__ dWhh1, const void* __restrict__ db1,
    const void* __restrict__ qW, const void* __restrict__ qb,
    const float* __restrict__ ctx,
    u64* __restrict__ H0d, u64* __restrict__ H1d, u64* __restrict__ dinpG,
    void* __restrict__ out, const int* __restrict__ flagp) {
  __shared__ u16 sAhi[16 * 264], sAlo[16 * 264], sBhi[16 * 264], sBlo[16 * 264];
  __shared__ float gb[16 * 64];
  __shared__ float dinpS[16];

  const int isbf = *flagp;
  const int tid = threadIdx.x, blk = blockIdx.x;
  const int grp = blk & 15, gs = blk >> 4;
  const int lane = tid & 63, wv = tid >> 6;
  const int ln = lane & 15, lq = lane >> 4;

  v8s W0F[8], W1F[16];
  {
    const int gw = wv * 256 + gs * 16 + ln;
    const int kq = lq * 8;
#pragma unroll
    for (int kt = 0; kt < 8; ++kt) {
      W0F[kt]     = ld8hi(dWhh0, (size_t)gw * 256 + kt * 32 + kq, isbf);
      W1F[kt]     = ld8hi(dWhh1, (size_t)gw * 256 + kt * 32 + kq, isbf);
      W1F[kt + 8] = ld8hi(dWih1, (size_t)gw * 256 + kt * 32 + kq, isbf);
    }
  }
  const int urow = tid >> 4, uu = tid & 15;
  float bg0[4], bg1[4], w0v[4];
#pragma unroll
  for (int g = 0; g < 4; ++g) {
    bg0[g] = ldIn(db0, g * 256 + gs * 16 + uu, isbf);
    bg1[g] = ldIn(db1, g * 256 + gs * 16 + uu, isbf);
    w0v[g] = ldIn(dWih0, g * 256 + gs * 16 + uu, isbf);
  }
  const int gRowU = grp * 16 + urow;
  const int gUnit = gs * 16 + uu;

  float c0 = ctx[(size_t)gRowU * 256 + gUnit];
  float c1 = c0;

#pragma unroll 1
  for (int t = 0; t < 24; ++t) {
    const int pPrev = (t + 1) & 1, pCur = t & 1;
    // ---- sub-step A: layer-0 cell ----
    if (t == 0) {
      stage_f32(sAhi, sAlo, ctx + (size_t)grp * 16 * 256, tid);
      if (tid < 16)
        dinpS[tid] = ldIn(x, ((size_t)(grp * 16 + tid) * 512 + 511) * 32 + 31, isbf);
    } else {
      stage_dec(sAhi, sAlo, H0d + (size_t)pPrev * 65536 + grp * 4096, tid, (u32)(2 * t - 1));
      if (tid < 16) {
        u64 w;
        do { w = aload64(dinpG + pPrev * 256 + grp * 16 + tid); } while ((u32)(w >> 32) != (u32)(2 * t));
        dinpS[tid] = __uint_as_float((u32)w);
      }
    }
    __syncthreads();
    v4f acc = {0, 0, 0, 0};
#pragma unroll
    for (int kt = 0; kt < 8; ++kt) {
      const int off = ln * 264 + kt * 32 + lq * 8;
      acc = MFMA(*(const v8s*)(sAhi + off), W0F[kt], acc);
      acc = MFMA(*(const v8s*)(sAlo + off), W0F[kt], acc);
    }
    {
      const int bR = lq * 4;
#pragma unroll
      for (int r = 0; r < 4; ++r) gb[(bR + r) * 64 + ln * 4 + wv] = acc[r];
    }
    float di = dinpS[urow];   // hoisted: dinpS not read after sync
    __syncthreads();
    {
      const float* g0 = gb + (urow * 16 + uu) * 4;
      float gi = g0[0] + bg0[0] + di * w0v[0];
      float gf = g0[1] + bg0[1] + di * w0v[1];
      float gg = g0[2] + bg0[2] + di * w0v[2];
      float go = g0[3] + bg0[3] + di * w0v[3];
      c0 = sigf(gf) * c0 + sigf(gi) * tanhfast(gg);
      float h = sigf(go) * tanhfast(c0);
      u16 hh = f2bf(h); u16 hl = f2bf(h - bf2f(hh));
      astore64(H0d + (size_t)pCur * 65536 + gRowU * 256 + gUnit,
               (u64)hh | ((u64)hl << 16) | ((u64)(u32)(2 * t + 1) << 32));
    }
    // ---- sub-step B: layer-1 cell ----
    if (t == 0) stage_f32(sBhi, sBlo, ctx + (size_t)grp * 16 * 256, tid);
    else stage_dec(sBhi, sBlo, H1d + (size_t)pPrev * 65536 + grp * 4096, tid, (u32)(2 * t));
    stage_dec(sAhi, sAlo, H0d + (size_t)pCur * 65536 + grp * 4096, tid, (u32)(2 * t + 1));
    __syncthreads();
    v4f a1 = {0, 0, 0, 0};
#pragma unroll
    for (int kt = 0; kt < 8; ++kt) {
      const int off = ln * 264 + kt * 32 + lq * 8;
      a1 = MFMA(*(const v8s*)(sBhi + off), W1F[kt], a1);
      a1 = MFMA(*(const v8s*)(sBlo + off), W1F[kt], a1);
      a1 = MFMA(*(const v8s*)(sAhi + off), W1F[kt + 8], a1);
      a1 = MFMA(*(const v8s*)(sAlo + off), W1F[kt + 8], a1);
    }
    {
      const int bR = lq * 4;
#pragma unroll
      for (int r = 0; r < 4; ++r) gb[(bR + r) * 64 + ln * 4 + wv] = a1[r];
    }
    __syncthreads();
    {
      const float* g1 = gb + (urow * 16 + uu) * 4;
      float gi = g1[0] + bg1[0], gf = g1[1] + bg1[1], gg = g1[2] + bg1[2], go = g1[3] + bg1[3];
      c1 = sigf(gf) * c1 + sigf(gi) * tanhfast(gg);
      float h = sigf(go) * tanhfast(c1);
      u16 hh = f2bf(h); u16 hl = f2bf(h - bf2f(hh));
      astore64(H1d + (size_t)pCur * 65536 + gRowU * 256 + gUnit,
               (u64)hh | ((u64)hl << 16) | ((u64)(u32)(2 * t + 2) << 32));
      if (gUnit == 0)
        astore64(dinpG + pCur * 256 + gRowU,
                 (u64)__float_as_uint(h) | ((u64)(u32)(2 * t + 2) << 32));
    }
  }
  // projection: stage h1d[23] (parity 1, tag 48) into LDS, then compute
  stage_dec(sAhi, sAlo, H1d + (size_t)65536 + grp * 4096, tid, 48u);
  __syncthreads();
  if (gs < 12 && tid < 96) {
    int r = tid / 6, p = tid % 6;
    int qo = gs * 6 + p, row = grp * 16 + r;
    float s = ldIn(qb, qo, isbf);
    for (int h = 0; h < 256; ++h)
      s += (bf2f(sAhi[r * 264 + h]) + bf2f(sAlo[r * 264 + h])) * ldIn(qW, (size_t)qo * 256 + h, isbf);
    if (isbf) ((u16*)out)[row * 72 + qo] = f2bf(s);
    else      ((float*)out)[row * 72 + qo] = s;
  }
}

extern "C" void kernel_launch(void* const* d_in, const int* in_sizes, int n_in,
                              void* d_out, int out_size, void* d_ws, size_t ws_size,
                              hipStream_t stream) {
  const void* x     = d_in[0];
  const void* eWih0 = d_in[1];
  const void* eWhh0 = d_in[2];
  const void* eb0   = d_in[3];
  const void* eWih1 = d_in[4];
  const void* eWhh1 = d_in[5];
  const void* eb1   = d_in[6];
  const void* dWih0 = d_in[7];
  const void* dWhh0 = d_in[8];
  const void* db0   = d_in[9];
  const void* dWih1 = d_in[10];
  const void* dWhh1 = d_in[11];
  const void* db1   = d_in[12];
  const void* aW    = d_in[13];
  const void* aV    = d_in[14];
  const void* qW    = d_in[15];
  const void* qb    = d_in[16];

  char* wsb = (char*)d_ws;
  u32*   H0    = (u32*)(wsb + 0);              // [2][16grp][16gs][16row][16] u32 = 524288 B
  u32*   H1    = (u32*)(wsb + 524288);         // 524288  -> 1048576
  u32*   H0tag = (u32*)(wsb + 1048576);        // [16grp][32] u32 = 2048 -> 1050624
  u32*   H1tag = (u32*)(wsb + 1050624);        // 2048    -> 1052672
  int*   flag  = (int*)(wsb + 1052672);        // 256     -> 1052928
  float* ctx   = (float*)(wsb + 1052928);      // 262144  -> 1315072
  u64*   dinpG = (u64*)(wsb + 1315072);        // [2][256] u64 = 4096 -> 1319168
  // dec-only buffers; H0d overlaps enc H0/H1 (disjoint kernel lifetimes; memset
  // re-zeroes each launch; enc residue tags >=511 can't alias dec tags <=48).
  u64*   H0d   = (u64*)(wsb + 0);              // [2][256][256] u64 = 1048576
  u64*   H1d   = (u64*)(wsb + 1319168);        // 1048576 -> 2367744
  // total ws: 2,367,744 bytes

  // zero H0/H1 payloads + sentinels (tag 0 == expected at t=0)
  hipMemsetAsync(wsb, 0, 1052672, stream);

  sniff_kernel<<<1, 256, 0, stream>>>((const u16*)eWhh0, flag);
  enc_kernel<<<256, 256, 0, stream>>>(x, eWih0, eWhh0, eb0, eWih1, eWhh1, eb1,
                                      aW, aV, H0, H1, H0tag, H1tag, ctx, flag);
  dec_kernel<<<256, 256, 0, stream>>>(x, dWih0, dWhh0, db0, dWih1, dWhh1, db1,
                                      qW, qb, ctx, H0d, H1d, dinpG,
                                      d_out, flag);
}

// Round 3
// 2558.728 us; speedup vs baseline: 1.0700x; 1.0700x over previous
//
#include <hip/hip_runtime.h>

typedef unsigned short u16;
typedef unsigned int u32;
typedef unsigned long long u64;
typedef short v8s __attribute__((ext_vector_type(8)));
typedef float v4f __attribute__((ext_vector_type(4)));

// Dims: B=256, T=512, D=32, H=256, 4H=1024, A=128, HOR=24, NQ=3
// Encoder: 512 blocks, 2 roles. Blocks 0..255 = L0 recurrence (h0), blocks
// 256..511 = L1 recurrence (h1) + attention. Roles pipeline: L0 streams h0
// through an 8-deep ring; L1 consumes it ~8 steps behind, so L1's only
// latency-critical wait is its own h1 island exchange. Direct tagged-payload
// spins (round-0 proven). L0 flow-controlled by per-grp progress (s_sleep poll).

__device__ __forceinline__ float bf2f(u16 u) { union { u32 u; float f; } c; c.u = ((u32)u) << 16; return c.f; }
__device__ __forceinline__ u16 f2bf(float f) {
  union { float f; u32 u; } c; c.f = f;
  u32 r = c.u + 0x7FFFu + ((c.u >> 16) & 1u);   // RTNE
  return (u16)(r >> 16);
}
__device__ __forceinline__ float sigf(float x) { return 1.f / (1.f + __expf(-x)); }
__device__ __forceinline__ float tanhfast(float x) {
  x = fminf(15.f, fmaxf(-15.f, x));
  float e = __expf(2.f * x);
  return (e - 1.f) / (e + 1.f);
}
__device__ __forceinline__ float ldIn(const void* p, size_t i, int isbf) {
  return isbf ? bf2f(((const u16*)p)[i]) : ((const float*)p)[i];
}
__device__ __forceinline__ v8s ld8hi(const void* p, size_t e, int isbf) {
  if (isbf) return *(const v8s*)((const u16*)p + e);
  const float* f = (const float*)p + e;
  v8s r;
#pragma unroll
  for (int j = 0; j < 8; ++j) r[j] = (short)f2bf(f[j]);
  return r;
}
__device__ __forceinline__ void ld8split(const void* p, size_t e, int isbf, v8s& hi, v8s& lo) {
  if (isbf) {
    hi = *(const v8s*)((const u16*)p + e);
    lo = v8s{0, 0, 0, 0, 0, 0, 0, 0};
  } else {
    const float* f = (const float*)p + e;
#pragma unroll
    for (int j = 0; j < 8; ++j) {
      u16 h = f2bf(f[j]);
      hi[j] = (short)h;
      lo[j] = (short)f2bf(f[j] - bf2f(h));
    }
  }
}
#define MFMA(a, b, c) __builtin_amdgcn_mfma_f32_16x16x32_bf16(a, b, c, 0, 0, 0)

__device__ __forceinline__ u64 aload64(const u64* p) {
  return __hip_atomic_load(p, __ATOMIC_RELAXED, __HIP_MEMORY_SCOPE_AGENT);
}
__device__ __forceinline__ u32 aload32(const u32* p) {
  return __hip_atomic_load(p, __ATOMIC_RELAXED, __HIP_MEMORY_SCOPE_AGENT);
}
__device__ __forceinline__ void astore32(u32* p, u32 v) {
  __hip_atomic_store(p, v, __ATOMIC_RELAXED, __HIP_MEMORY_SCOPE_AGENT);
}
__device__ __forceinline__ void astore64(u64* p, u64 v) {
  __hip_atomic_store(p, v, __ATOMIC_RELAXED, __HIP_MEMORY_SCOPE_AGENT);
}

// Payload: [grp][gs(16)][row(16)][16 units] u32 (writer-exclusive 1KB runs),
// word = bf16 | tag<<16. Reader loads its grp slice as 8 u64/thread.
__device__ __forceinline__ void load8(u64* v, const u32* src, int tid) {
  const u64* p = (const u64*)src;
#pragma unroll
  for (int i = 0; i < 8; ++i) v[i] = aload64(p + i * 256 + tid);
}
// Spin until every embedded tag matches, then unpack to LDS [row][264 u16].
__device__ __forceinline__ void verify_unpack(u16* dst, const u32* src, u64* v,
                                              int tid, u32 tag) {
  const u64* p = (const u64*)src;
  bool all;
  do {
    all = true;
#pragma unroll
    for (int i = 0; i < 8; ++i) {
      u64 w = v[i];
      if (!((((w >> 16) & 0xFFFFull) == tag) && ((w >> 48) == tag))) {
        all = false;
        v[i] = aload64(p + i * 256 + tid);
      }
    }
  } while (!all);
#pragma unroll
  for (int i = 0; i < 8; ++i) {
    int idx = i * 256 + tid;
    int gs2 = idx >> 7, row = (idx >> 3) & 15, c = idx & 7;
    u64 w = v[i];
    ((u32*)(dst + row * 264))[gs2 * 8 + c] =
        (u32)(w & 0xFFFF) | ((((u32)(w >> 32)) & 0xFFFF) << 16);
  }
}

// ---- Decoder tagged stage (unchanged): u64/unit = hi | lo<<16 | tag<<32, [16][256] u64.
__device__ __forceinline__ void stage_dec(u16* dhi, u16* dlo, const u64* src,
                                          int tid, u32 tag) {
  u64 v[16];
#pragma unroll
  for (int i = 0; i < 16; ++i) v[i] = aload64(src + i * 256 + tid);
  bool all;
  do {
    all = true;
#pragma unroll
    for (int i = 0; i < 16; ++i) {
      if ((u32)(v[i] >> 32) != tag) { all = false; v[i] = aload64(src + i * 256 + tid); }
    }
  } while (!all);
#pragma unroll
  for (int i = 0; i < 16; ++i) {
    int idx = i * 256 + tid;
    int row = idx >> 8, col = idx & 255;
    dhi[row * 264 + col] = (u16)v[i];
    dlo[row * 264 + col] = (u16)(v[i] >> 16);
  }
}
__device__ __forceinline__ void stage_f32(u16* dhi, u16* dlo, const float* src, int tid) {
#pragma unroll
  for (int i = 0; i < 8; ++i) {
    int e = i * 512 + tid * 2;
    int row = e >> 8, jc = e & 255;
    float f0 = src[row * 256 + jc], f1 = src[row * 256 + jc + 1];
    u16 h0 = f2bf(f0), h1 = f2bf(f1);
    u16 l0 = f2bf(f0 - bf2f(h0)), l1 = f2bf(f1 - bf2f(h1));
    ((u32*)(dhi + row * 264))[jc >> 1] = (u32)h0 | ((u32)h1 << 16);
    ((u32*)(dlo + row * 264))[jc >> 1] = (u32)l0 | ((u32)l1 << 16);
  }
}

__global__ void sniff_kernel(const u16* __restrict__ w, int* __restrict__ flag) {
  __shared__ int cnt;
  if (threadIdx.x == 0) cnt = 0;
  __syncthreads();
  int ok = 0;
  for (int i = threadIdx.x; i < 1024; i += 256) {
    u16 u = w[2 * i];
    int e = (u >> 7) & 0xFF;
    ok += (u == 0 || (e >= 97 && e <= 140)) ? 1 : 0;
  }
  atomicAdd(&cnt, ok);
  __syncthreads();
  if (threadIdx.x == 0) *flag = (cnt >= 768) ? 1 : 0;
}

// ---------------- Encoder: 512 blocks, L0 role (h0 pipe) + L1 role (h1+attn pipe) --
__global__ __launch_bounds__(256, 2) void enc_kernel(
    const void* __restrict__ x,
    const void* __restrict__ eWih0, const void* __restrict__ eWhh0, const void* __restrict__ eb0,
    const void* __restrict__ eWih1, const void* __restrict__ eWhh1, const void* __restrict__ eb1,
    const void* __restrict__ aW, const void* __restrict__ aV,
    u32* __restrict__ stream, u32* __restrict__ H0par, u32* __restrict__ H1par,
    u32* __restrict__ prog1,
    float* __restrict__ ctx, const int* __restrict__ flagp) {
  __shared__ __align__(16) u16 hAs[16 * 264];   // L0: h0[t-1] | L1: h1[s-1]
  __shared__ __align__(16) u16 hBs[16 * 264];   // L1 only: streamed h0[s]
  __shared__ float gb[16 * 64];
  __shared__ float eP[16 * 132];                // L1 only

  const int isbf = *flagp;
  const int tid = threadIdx.x, blk = blockIdx.x;
  const bool isL1 = blk >= 256;
  const int b = isL1 ? blk - 256 : blk;
  const int grp = b & 15, gs = b >> 4;
  const int lane = tid & 63, wv = tid >> 6;      // wave = gate index
  const int ln = lane & 15, lq = lane >> 4;
  const int urow = tid >> 4, uu = tid & 15;
  const int gRowU = grp * 16 + urow;
  const int gUnit = gs * 16 + uu;
  const u32 stOff = (u32)(grp * 4096 + gs * 256 + urow * 16 + uu);

  if (!isL1) {
    // =================== L0 role: h0 recurrence ===================
    v8s W0F[9];
    {
      const int gw = wv * 256 + gs * 16 + ln;
      const int kq = lq * 8;
      W0F[0] = ld8hi(eWih0, (size_t)gw * 32 + kq, isbf);
#pragma unroll
      for (int kt = 0; kt < 8; ++kt)
        W0F[kt + 1] = ld8hi(eWhh0, (size_t)gw * 256 + kt * 32 + kq, isbf);
    }
    float bg0[4];
#pragma unroll
    for (int g = 0; g < 4; ++g) bg0[g] = ldIn(eb0, g * 256 + gs * 16 + uu, isbf);
    const int aRow = grp * 16 + ln;
    float c0 = 0.f;
    v8s xh_c, xl_c;
    ld8split(x, ((size_t)aRow * 512) * 32 + lq * 8, isbf, xh_c, xl_c);

#pragma unroll 1
    for (int t = 0; t < 512; ++t) {
      const int rPar = (t + 1) & 1, wPar = t & 1;
      // spin h0[t-1] (t=0: zeros tag 0)
      {
        const u32* srcH = H0par + (size_t)rPar * 65536 + grp * 4096;
        u64 v[8];
        load8(v, srcH, tid);
        verify_unpack(hAs, srcH, v, tid, (u32)(u16)t);
      }
      __syncthreads();                                 // b1: h0s ready
      v4f acc0 = {0, 0, 0, 0};
      acc0 = MFMA(xh_c, W0F[0], acc0);
      if (!isbf) acc0 = MFMA(xl_c, W0F[0], acc0);
#pragma unroll
      for (int kt = 0; kt < 8; ++kt) {
        v8s a = *(const v8s*)(hAs + ln * 264 + kt * 32 + lq * 8);
        acc0 = MFMA(a, W0F[kt + 1], acc0);
      }
#pragma unroll
      for (int r = 0; r < 4; ++r) gb[(lq * 4 + r) * 64 + ln * 4 + wv] = acc0[r];
      // x prefetch t+1 (in flight across throttle/barrier)
      v8s xh_n, xl_n;
      {
        int tn = (t + 1 < 512) ? t + 1 : 511;
        ld8split(x, ((size_t)aRow * 512 + tn) * 32 + lq * 8, isbf, xh_n, xl_n);
      }
      // throttle: don't overwrite stream slot until all L1 consumed h0[t-8]
      if (t >= 8) {
        u32 p = aload32(prog1 + grp * 16 + (lane & 15));
        while (!__all((int)p >= t - 7)) {
          __builtin_amdgcn_s_sleep(2);
          p = aload32(prog1 + grp * 16 + (lane & 15));
        }
      }
      __syncthreads();                                 // b2: gb ready
      {
        const float* g0 = gb + (urow * 16 + uu) * 4;
        float gi = g0[0] + bg0[0], gf = g0[1] + bg0[1];
        float gg = g0[2] + bg0[2], go = g0[3] + bg0[3];
        c0 = sigf(gf) * c0 + sigf(gi) * tanhfast(gg);
        float h = sigf(go) * tanhfast(c0);
        u32 w = (u32)f2bf(h) | ((u32)(u16)(t + 1) << 16);
        astore32(H0par + (size_t)wPar * 65536 + stOff, w);
        astore32(stream + (size_t)(t & 7) * 65536 + stOff, w);
      }
      xh_c = xh_n; xl_c = xl_n;
    }
  } else {
    // =============== L1 role: h1 recurrence + attention ===============
    v8s W1F[16], AWF[16];
    {
      const int gw = wv * 256 + gs * 16 + ln;
      const int kq = lq * 8;
#pragma unroll
      for (int kt = 0; kt < 8; ++kt) {
        W1F[kt]     = ld8hi(eWhh1, (size_t)gw * 256 + kt * 32 + kq, isbf);
        W1F[kt + 8] = ld8hi(eWih1, (size_t)gw * 256 + kt * 32 + kq, isbf);
      }
#pragma unroll
      for (int kt = 0; kt < 8; ++kt)
#pragma unroll
        for (int j2 = 0; j2 < 2; ++j2) {
          v8s f;
          int ac = (2 * wv + j2) * 16 + ln;
#pragma unroll
          for (int j = 0; j < 8; ++j)
            f[j] = (short)f2bf(ldIn(aW, (size_t)(kt * 32 + kq + j) * 128 + ac, isbf));
          AWF[kt * 2 + j2] = f;
        }
    }
    float bg1[4], aVr[8];
#pragma unroll
    for (int g = 0; g < 4; ++g) bg1[g] = ldIn(eb1, g * 256 + gs * 16 + uu, isbf);
#pragma unroll
    for (int j = 0; j < 8; ++j) aVr[j] = ldIn(aV, (size_t)(uu + 16 * j), isbf);

    // zero h1s (= h1[-1])
    for (int i = tid; i < 2112; i += 256) ((u32*)hAs)[i] = 0;

    float c1 = 0.f, mS = -3e38f, lS = 0.f, ctxA = 0.f;

#pragma unroll 1
    for (int s = 0; s <= 512; ++s) {
      const int rPar = (s + 1) & 1, wPar = s & 1;
      // issue stream loads first (h0[s] is ~8 steps old: ready), then spin h1.
      const u32* srcS = stream + (size_t)(s & 7) * 65536 + grp * 4096;
      u64 vS[8];
      if (s < 512) load8(vS, srcS, tid);
      if (s >= 1) {
        const u32* srcH = H1par + (size_t)rPar * 65536 + grp * 4096;
        u64 vH[8];
        load8(vH, srcH, tid);
        verify_unpack(hAs, srcH, vH, tid, (u32)(u16)s);
      }
      if (s < 512) verify_unpack(hBs, srcS, vS, tid, (u32)(u16)(s + 1));
      __syncthreads();                                 // b1: hAs/hBs ready
      if (tid == 0) astore32(prog1 + grp * 16 + gs, (u32)(s + 1));

      v4f acc1 = {0, 0, 0, 0}, accA0 = {0, 0, 0, 0}, accA1 = {0, 0, 0, 0};
#pragma unroll
      for (int kt = 0; kt < 8; ++kt) {
        v8s a1 = *(const v8s*)(hAs + ln * 264 + kt * 32 + lq * 8);
        if (s < 512) {
          v8s a0 = *(const v8s*)(hBs + ln * 264 + kt * 32 + lq * 8);
          acc1 = MFMA(a0, W1F[kt + 8], acc1);
          acc1 = MFMA(a1, W1F[kt], acc1);
        }
        if (s >= 1) {
          accA0 = MFMA(a1, AWF[kt * 2], accA0);
          accA1 = MFMA(a1, AWF[kt * 2 + 1], accA1);
        }
      }
      if (s < 512) {
#pragma unroll
        for (int r = 0; r < 4; ++r) gb[(lq * 4 + r) * 64 + ln * 4 + wv] = acc1[r];
      }
      if (s >= 1) {
#pragma unroll
        for (int r = 0; r < 4; ++r) {
          eP[(lq * 4 + r) * 132 + (2 * wv) * 16 + ln] = accA0[r];
          eP[(lq * 4 + r) * 132 + (2 * wv + 1) * 16 + ln] = accA1[r];
        }
      }
      float h1v = bf2f(hAs[urow * 264 + gUnit]);       // hoisted before b2
      __syncthreads();                                 // b2: gb/eP ready
      if (s < 512) {
        const float* g1 = gb + (urow * 16 + uu) * 4;
        float gi = g1[0] + bg1[0], gf = g1[1] + bg1[1];
        float gg = g1[2] + bg1[2], go = g1[3] + bg1[3];
        c1 = sigf(gf) * c1 + sigf(gi) * tanhfast(gg);
        float h = sigf(go) * tanhfast(c1);
        astore32(H1par + (size_t)wPar * 65536 + stOff,
                 (u32)f2bf(h) | ((u32)(u16)(s + 1) << 16));
      }
      if (s >= 1) {
        float e = 0.f;
#pragma unroll
        for (int j = 0; j < 8; ++j)
          e += tanhfast(eP[urow * 132 + uu + 16 * j]) * aVr[j];
        e += __shfl_xor(e, 1);
        e += __shfl_xor(e, 2);
        e += __shfl_xor(e, 4);
        e += __shfl_xor(e, 8);
        float nm = fmaxf(mS, e);
        float al = __expf(mS - nm), p = __expf(e - nm);
        lS = lS * al + p;
        ctxA = ctxA * al + p * h1v;
        mS = nm;
      }
    }
    ctx[(size_t)gRowU * 256 + gUnit] = ctxA / lS;
  }
}

// ---------------- Decoder: 24 steps x 2 sub-steps + projection (hi/lo, tagged u64) -
__global__ __launch_bounds__(256, 1) void dec_kernel(
    const void* __restrict__ x,
    const void* __restrict__ dWih0, const void* __restrict__ dWhh0, const void* __restrict__ db0,
    const void* __restrict__ dWih1, const void* __restrict__ dWhh1, const void* __restrict__ db1,
    const void* __restrict__ qW, const void* __restrict__ qb,
    const float* __restrict__ ctx,
    u64* __restrict__ H0d, u64* __restrict__ H1d, u64* __restrict__ dinpG,
    void* __restrict__ out, const int* __restrict__ flagp) {
  __shared__ u16 sAhi[16 * 264], sAlo[16 * 264], sBhi[16 * 264], sBlo[16 * 264];
  __shared__ float gb[16 * 64];
  __shared__ float dinpS[16];

  const int isbf = *flagp;
  const int tid = threadIdx.x, blk = blockIdx.x;
  const int grp = blk & 15, gs = blk >> 4;
  const int lane = tid & 63, wv = tid >> 6;
  const int ln = lane & 15, lq = lane >> 4;

  v8s W0F[8], W1F[16];
  {
    const int gw = wv * 256 + gs * 16 + ln;
    const int kq = lq * 8;
#pragma unroll
    for (int kt = 0; kt < 8; ++kt) {
      W0F[kt]     = ld8hi(dWhh0, (size_t)gw * 256 + kt * 32 + kq, isbf);
      W1F[kt]     = ld8hi(dWhh1, (size_t)gw * 256 + kt * 32 + kq, isbf);
      W1F[kt + 8] = ld8hi(dWih1, (size_t)gw * 256 + kt * 32 + kq, isbf);
    }
  }
  const int urow = tid >> 4, uu = tid & 15;
  float bg0[4], bg1[4], w0v[4];
#pragma unroll
  for (int g = 0; g < 4; ++g) {
    bg0[g] = ldIn(db0, g * 256 + gs * 16 + uu, isbf);
    bg1[g] = ldIn(db1, g * 256 + gs * 16 + uu, isbf);
    w0v[g] = ldIn(dWih0, g * 256 + gs * 16 + uu, isbf);
  }
  const int gRowU = grp * 16 + urow;
  const int gUnit = gs * 16 + uu;

  float c0 = ctx[(size_t)gRowU * 256 + gUnit];
  float c1 = c0;

#pragma unroll 1
  for (int t = 0; t < 24; ++t) {
    const int pPrev = (t + 1) & 1, pCur = t & 1;
    // ---- sub-step A: layer-0 cell ----
    if (t == 0) {
      stage_f32(sAhi, sAlo, ctx + (size_t)grp * 16 * 256, tid);
      if (tid < 16)
        dinpS[tid] = ldIn(x, ((size_t)(grp * 16 + tid) * 512 + 511) * 32 + 31, isbf);
    } else {
      stage_dec(sAhi, sAlo, H0d + (size_t)pPrev * 65536 + grp * 4096, tid, (u32)(2 * t - 1));
      if (tid < 16) {
        u64 w;
        do { w = aload64(dinpG + pPrev * 256 + grp * 16 + tid); } while ((u32)(w >> 32) != (u32)(2 * t));
        dinpS[tid] = __uint_as_float((u32)w);
      }
    }
    __syncthreads();
    v4f acc = {0, 0, 0, 0};
#pragma unroll
    for (int kt = 0; kt < 8; ++kt) {
      const int off = ln * 264 + kt * 32 + lq * 8;
      acc = MFMA(*(const v8s*)(sAhi + off), W0F[kt], acc);
      acc = MFMA(*(const v8s*)(sAlo + off), W0F[kt], acc);
    }
    {
      const int bR = lq * 4;
#pragma unroll
      for (int r = 0; r < 4; ++r) gb[(bR + r) * 64 + ln * 4 + wv] = acc[r];
    }
    float di = dinpS[urow];   // hoisted: dinpS not read after sync
    __syncthreads();
    {
      const float* g0 = gb + (urow * 16 + uu) * 4;
      float gi = g0[0] + bg0[0] + di * w0v[0];
      float gf = g0[1] + bg0[1] + di * w0v[1];
      float gg = g0[2] + bg0[2] + di * w0v[2];
      float go = g0[3] + bg0[3] + di * w0v[3];
      c0 = sigf(gf) * c0 + sigf(gi) * tanhfast(gg);
      float h = sigf(go) * tanhfast(c0);
      u16 hh = f2bf(h); u16 hl = f2bf(h - bf2f(hh));
      astore64(H0d + (size_t)pCur * 65536 + gRowU * 256 + gUnit,
               (u64)hh | ((u64)hl << 16) | ((u64)(u32)(2 * t + 1) << 32));
    }
    // ---- sub-step B: layer-1 cell ----
    if (t == 0) stage_f32(sBhi, sBlo, ctx + (size_t)grp * 16 * 256, tid);
    else stage_dec(sBhi, sBlo, H1d + (size_t)pPrev * 65536 + grp * 4096, tid, (u32)(2 * t));
    stage_dec(sAhi, sAlo, H0d + (size_t)pCur * 65536 + grp * 4096, tid, (u32)(2 * t + 1));
    __syncthreads();
    v4f a1 = {0, 0, 0, 0};
#pragma unroll
    for (int kt = 0; kt < 8; ++kt) {
      const int off = ln * 264 + kt * 32 + lq * 8;
      a1 = MFMA(*(const v8s*)(sBhi + off), W1F[kt], a1);
      a1 = MFMA(*(const v8s*)(sBlo + off), W1F[kt], a1);
      a1 = MFMA(*(const v8s*)(sAhi + off), W1F[kt + 8], a1);
      a1 = MFMA(*(const v8s*)(sAlo + off), W1F[kt + 8], a1);
    }
    {
      const int bR = lq * 4;
#pragma unroll
      for (int r = 0; r < 4; ++r) gb[(bR + r) * 64 + ln * 4 + wv] = a1[r];
    }
    __syncthreads();
    {
      const float* g1 = gb + (urow * 16 + uu) * 4;
      float gi = g1[0] + bg1[0], gf = g1[1] + bg1[1], gg = g1[2] + bg1[2], go = g1[3] + bg1[3];
      c1 = sigf(gf) * c1 + sigf(gi) * tanhfast(gg);
      float h = sigf(go) * tanhfast(c1);
      u16 hh = f2bf(h); u16 hl = f2bf(h - bf2f(hh));
      astore64(H1d + (size_t)pCur * 65536 + gRowU * 256 + gUnit,
               (u64)hh | ((u64)hl << 16) | ((u64)(u32)(2 * t + 2) << 32));
      if (gUnit == 0)
        astore64(dinpG + pCur * 256 + gRowU,
                 (u64)__float_as_uint(h) | ((u64)(u32)(2 * t + 2) << 32));
    }
  }
  // projection: stage h1d[23] (parity 1, tag 48) into LDS, then compute
  stage_dec(sAhi, sAlo, H1d + (size_t)65536 + grp * 4096, tid, 48u);
  __syncthreads();
  if (gs < 12 && tid < 96) {
    int r = tid / 6, p = tid % 6;
    int qo = gs * 6 + p, row = grp * 16 + r;
    float s = ldIn(qb, qo, isbf);
    for (int h = 0; h < 256; ++h)
      s += (bf2f(sAhi[r * 264 + h]) + bf2f(sAlo[r * 264 + h])) * ldIn(qW, (size_t)qo * 256 + h, isbf);
    if (isbf) ((u16*)out)[row * 72 + qo] = f2bf(s);
    else      ((float*)out)[row * 72 + qo] = s;
  }
}

extern "C" void kernel_launch(void* const* d_in, const int* in_sizes, int n_in,
                              void* d_out, int out_size, void* d_ws, size_t ws_size,
                              hipStream_t stream_) {
  const void* x     = d_in[0];
  const void* eWih0 = d_in[1];
  const void* eWhh0 = d_in[2];
  const void* eb0   = d_in[3];
  const void* eWih1 = d_in[4];
  const void* eWhh1 = d_in[5];
  const void* eb1   = d_in[6];
  const void* dWih0 = d_in[7];
  const void* dWhh0 = d_in[8];
  const void* db0   = d_in[9];
  const void* dWih1 = d_in[10];
  const void* dWhh1 = d_in[11];
  const void* db1   = d_in[12];
  const void* aW    = d_in[13];
  const void* aV    = d_in[14];
  const void* qW    = d_in[15];
  const void* qb    = d_in[16];

  char* wsb = (char*)d_ws;
  u32*   strm  = (u32*)(wsb + 0);              // [8 slots][grp][gs][row][16] u32 = 2,097,152 B
  u32*   H0par = (u32*)(wsb + 2097152);        // [2][...] = 524,288 -> 2,621,440
  u32*   H1par = (u32*)(wsb + 2621440);        // 524,288 -> 3,145,728
  u32*   prog1 = (u32*)(wsb + 3145728);        // [16grp][16] u32 = 1,024 -> 3,146,752
  int*   flag  = (int*)(wsb + 3146752);        // 256 -> 3,147,008
  float* ctx   = (float*)(wsb + 3147008);      // 262,144 -> 3,409,152
  u64*   dinpG = (u64*)(wsb + 3409152);        // 4,096 -> 3,413,248
  // dec-only buffers overlay the stream region (disjoint kernel lifetimes;
  // enc residual u32-pair "tags" in high word are >= 65536, never equal to
  // dec's expected small tags, so dec spins until its own writes land).
  u64*   H0d   = (u64*)(wsb + 0);              // 1,048,576
  u64*   H1d   = (u64*)(wsb + 1048576);        // 1,048,576 -> 2,097,152
  // total ws: 3,413,248 bytes

  // zero stream + parities + progress (tag 0 == expected at t=0)
  hipMemsetAsync(wsb, 0, 3146752, stream_);

  sniff_kernel<<<1, 256, 0, stream_>>>((const u16*)eWhh0, flag);
  enc_kernel<<<512, 256, 0, stream_>>>(x, eWih0, eWhh0, eb0, eWih1, eWhh1, eb1,
                                       aW, aV, strm, H0par, H1par, prog1, ctx, flag);
  dec_kernel<<<256, 256, 0, stream_>>>(x, dWih0, dWhh0, db0, dWih1, dWhh1, db1,
                                       qW, qb, ctx, H0d, H1d, dinpG,
                                       d_out, flag);
}

// Round 4
// 2363.429 us; speedup vs baseline: 1.1584x; 1.0826x over previous
//
#include <hip/hip_runtime.h>

typedef unsigned short u16;
typedef unsigned int u32;
typedef unsigned long long u64;
typedef short v8s __attribute__((ext_vector_type(8)));
typedef float v4f __attribute__((ext_vector_type(4)));

// Dims: B=256, T=512, D=32, H=256, 4H=1024, A=128, HOR=24, NQ=3
// 256 blocks = 16 groups (16 batch rows) x 16 slices. grp = blk&15 puts all 16
// slices of a grp on ONE XCD (stride-16 blocks, round-robin mapping) -> their
// shared L2 is the fast exchange medium. Writers DUAL-STORE h (plain store ->
// local L2 fast path, agent store -> LLC mirror). Readers poll the fast buffer
// with sc0 (L1-bypass, L2-hit) loads; every 4th round they poll the mirror with
// agent loads. Tags self-validate either source, so correctness never depends
// on the block->XCD mapping; only speed does.

__device__ __forceinline__ float bf2f(u16 u) { union { u32 u; float f; } c; c.u = ((u32)u) << 16; return c.f; }
__device__ __forceinline__ u16 f2bf(float f) {
  union { float f; u32 u; } c; c.f = f;
  u32 r = c.u + 0x7FFFu + ((c.u >> 16) & 1u);   // RTNE
  return (u16)(r >> 16);
}
__device__ __forceinline__ float sigf(float x) { return 1.f / (1.f + __expf(-x)); }
__device__ __forceinline__ float tanhfast(float x) {
  x = fminf(15.f, fmaxf(-15.f, x));
  float e = __expf(2.f * x);
  return (e - 1.f) / (e + 1.f);
}
__device__ __forceinline__ float ldIn(const void* p, size_t i, int isbf) {
  return isbf ? bf2f(((const u16*)p)[i]) : ((const float*)p)[i];
}
__device__ __forceinline__ v8s ld8hi(const void* p, size_t e, int isbf) {
  if (isbf) return *(const v8s*)((const u16*)p + e);
  const float* f = (const float*)p + e;
  v8s r;
#pragma unroll
  for (int j = 0; j < 8; ++j) r[j] = (short)f2bf(f[j]);
  return r;
}
__device__ __forceinline__ void ld8split(const void* p, size_t e, int isbf, v8s& hi, v8s& lo) {
  if (isbf) {
    hi = *(const v8s*)((const u16*)p + e);
    lo = v8s{0, 0, 0, 0, 0, 0, 0, 0};
  } else {
    const float* f = (const float*)p + e;
#pragma unroll
    for (int j = 0; j < 8; ++j) {
      u16 h = f2bf(f[j]);
      hi[j] = (short)h;
      lo[j] = (short)f2bf(f[j] - bf2f(h));
    }
  }
}
#define MFMA(a, b, c) __builtin_amdgcn_mfma_f32_16x16x32_bf16(a, b, c, 0, 0, 0)

__device__ __forceinline__ u64 aload64(const u64* p) {
  return __hip_atomic_load(p, __ATOMIC_RELAXED, __HIP_MEMORY_SCOPE_AGENT);
}
__device__ __forceinline__ void astore32(u32* p, u32 v) {
  __hip_atomic_store(p, v, __ATOMIC_RELAXED, __HIP_MEMORY_SCOPE_AGENT);
}
__device__ __forceinline__ void astore64(u64* p, u64 v) {
  __hip_atomic_store(p, v, __ATOMIC_RELAXED, __HIP_MEMORY_SCOPE_AGENT);
}

// ---- 8x u64 strided load, L1-bypass / L2-hit (sc0). Single asm block: loads
// issue, one waitcnt, values defined at asm end (no in-flight reg hazards).
__device__ __forceinline__ void load8_l2(u64* v, const u64* p, int tid) {
  const u64* a0 = p + tid;
  const u64* a1 = p + 256 + tid;
  const u64* a2 = p + 512 + tid;
  const u64* a3 = p + 768 + tid;
  const u64* a4 = p + 1024 + tid;
  const u64* a5 = p + 1280 + tid;
  const u64* a6 = p + 1536 + tid;
  const u64* a7 = p + 1792 + tid;
  asm volatile(
      "global_load_dwordx2 %0, %8, off sc0\n\t"
      "global_load_dwordx2 %1, %9, off sc0\n\t"
      "global_load_dwordx2 %2, %10, off sc0\n\t"
      "global_load_dwordx2 %3, %11, off sc0\n\t"
      "global_load_dwordx2 %4, %12, off sc0\n\t"
      "global_load_dwordx2 %5, %13, off sc0\n\t"
      "global_load_dwordx2 %6, %14, off sc0\n\t"
      "global_load_dwordx2 %7, %15, off sc0\n\t"
      "s_waitcnt vmcnt(0)"
      : "=&v"(v[0]), "=&v"(v[1]), "=&v"(v[2]), "=&v"(v[3]),
        "=&v"(v[4]), "=&v"(v[5]), "=&v"(v[6]), "=&v"(v[7])
      : "v"(a0), "v"(a1), "v"(a2), "v"(a3), "v"(a4), "v"(a5), "v"(a6), "v"(a7)
      : "memory");
}
// ---- agent-scope fallback (always-correct path)
__device__ __forceinline__ void load8(u64* v, const u32* src, int tid) {
  const u64* p = (const u64*)src;
#pragma unroll
  for (int i = 0; i < 8; ++i) v[i] = aload64(p + i * 256 + tid);
}

// Payload: [gs(16)][row(16)][16 units] u32 (writer-exclusive 1KB runs),
// word = bf16 | tag<<16. Hybrid poll until all tags match, unpack to LDS
// [row][264 u16] (u32 col = gs*8 + c).
__device__ __forceinline__ void poll_unpack(u16* dst, const u32* fb, const u32* mb,
                                            int tid, u32 tag) {
  u64 v[8];
  const u64* pf = (const u64*)fb;
  load8_l2(v, pf, tid);
  u32 round = 0;
  while (true) {
    bool ok = true;
#pragma unroll
    for (int i = 0; i < 8; ++i) {
      u64 w = v[i];
      ok &= ((((w >> 16) & 0xFFFFull) == tag) && ((w >> 48) == tag));
    }
    if (ok) break;
    ++round;
    if ((round & 3u) == 3u) load8(v, mb, tid);     // authoritative (LLC)
    else load8_l2(v, pf, tid);                     // cheap local-L2 probe
  }
#pragma unroll
  for (int i = 0; i < 8; ++i) {
    int idx = i * 256 + tid;
    int g2 = idx >> 7, row = (idx >> 3) & 15, c = idx & 7;
    u64 w = v[i];
    ((u32*)(dst + row * 264))[g2 * 8 + c] =
        (u32)(w & 0xFFFF) | ((((u32)(w >> 32)) & 0xFFFF) << 16);
  }
}

// ---- Decoder tagged stage (agent-only, proven): u64/unit = hi|lo<<16|tag<<32.
__device__ __forceinline__ void stage_dec(u16* dhi, u16* dlo, const u64* src,
                                          int tid, u32 tag) {
  u64 v[16];
#pragma unroll
  for (int i = 0; i < 16; ++i) v[i] = aload64(src + i * 256 + tid);
  bool all;
  do {
    all = true;
#pragma unroll
    for (int i = 0; i < 16; ++i) {
      if ((u32)(v[i] >> 32) != tag) { all = false; v[i] = aload64(src + i * 256 + tid); }
    }
  } while (!all);
#pragma unroll
  for (int i = 0; i < 16; ++i) {
    int idx = i * 256 + tid;
    int row = idx >> 8, col = idx & 255;
    dhi[row * 264 + col] = (u16)v[i];
    dlo[row * 264 + col] = (u16)(v[i] >> 16);
  }
}
__device__ __forceinline__ void stage_f32(u16* dhi, u16* dlo, const float* src, int tid) {
#pragma unroll
  for (int i = 0; i < 8; ++i) {
    int e = i * 512 + tid * 2;
    int row = e >> 8, jc = e & 255;
    float f0 = src[row * 256 + jc], f1 = src[row * 256 + jc + 1];
    u16 h0 = f2bf(f0), h1 = f2bf(f1);
    u16 l0 = f2bf(f0 - bf2f(h0)), l1 = f2bf(f1 - bf2f(h1));
    ((u32*)(dhi + row * 264))[jc >> 1] = (u32)h0 | ((u32)h1 << 16);
    ((u32*)(dlo + row * 264))[jc >> 1] = (u32)l0 | ((u32)l1 << 16);
  }
}

__global__ void sniff_kernel(const u16* __restrict__ w, int* __restrict__ flag) {
  __shared__ int cnt;
  if (threadIdx.x == 0) cnt = 0;
  __syncthreads();
  int ok = 0;
  for (int i = threadIdx.x; i < 1024; i += 256) {
    u16 u = w[2 * i];
    int e = (u >> 7) & 0xFF;
    ok += (u == 0 || (e >= 97 && e <= 140)) ? 1 : 0;
  }
  atomicAdd(&cnt, ok);
  __syncthreads();
  if (threadIdx.x == 0) *flag = (cnt >= 768) ? 1 : 0;
}

// ---------------- Encoder (both LSTM layers, pipelined) + fused online attention ---
__global__ __launch_bounds__(256, 1) void enc_kernel(
    const void* __restrict__ x,
    const void* __restrict__ eWih0, const void* __restrict__ eWhh0, const void* __restrict__ eb0,
    const void* __restrict__ eWih1, const void* __restrict__ eWhh1, const void* __restrict__ eb1,
    const void* __restrict__ aW, const void* __restrict__ aV,
    u32* __restrict__ H0f, u32* __restrict__ H1f,
    u32* __restrict__ H0m, u32* __restrict__ H1m,
    float* __restrict__ ctx, const int* __restrict__ flagp) {
  __shared__ __align__(16) u16 h0s[16 * 264], h1s[16 * 264];
  __shared__ float gb0[16 * 64], gb1[16 * 64];
  __shared__ float eP[16 * 132];

  const int isbf = *flagp;
  const int tid = threadIdx.x, blk = blockIdx.x;
  const int grp = blk & 15, gs = blk >> 4;      // grp slices share an XCD (stride 16)
  const int lane = tid & 63, wv = tid >> 6;     // wave = gate index
  const int ln = lane & 15, lq = lane >> 4;

  v8s W0F[9], W1F[16], AWF[16];
  {
    const int gw = wv * 256 + gs * 16 + ln;
    const int kq = lq * 8;
    W0F[0] = ld8hi(eWih0, (size_t)gw * 32 + kq, isbf);
#pragma unroll
    for (int kt = 0; kt < 8; ++kt) {
      W0F[kt + 1] = ld8hi(eWhh0, (size_t)gw * 256 + kt * 32 + kq, isbf);
      W1F[kt]     = ld8hi(eWhh1, (size_t)gw * 256 + kt * 32 + kq, isbf);
      W1F[kt + 8] = ld8hi(eWih1, (size_t)gw * 256 + kt * 32 + kq, isbf);
    }
#pragma unroll
    for (int kt = 0; kt < 8; ++kt)
#pragma unroll
      for (int j2 = 0; j2 < 2; ++j2) {
        v8s f;
        int ac = (2 * wv + j2) * 16 + ln;
#pragma unroll
        for (int j = 0; j < 8; ++j)
          f[j] = (short)f2bf(ldIn(aW, (size_t)(kt * 32 + kq + j) * 128 + ac, isbf));
        AWF[kt * 2 + j2] = f;
      }
  }

  const int urow = tid >> 4, uu = tid & 15;
  float bg0[4], bg1[4], aVr[8];
#pragma unroll
  for (int g = 0; g < 4; ++g) {
    bg0[g] = ldIn(eb0, g * 256 + gs * 16 + uu, isbf);
    bg1[g] = ldIn(eb1, g * 256 + gs * 16 + uu, isbf);
  }
#pragma unroll
  for (int j = 0; j < 8; ++j) aVr[j] = ldIn(aV, (size_t)(uu + 16 * j), isbf);

  const int gRowU = grp * 16 + urow;
  const int gUnit = gs * 16 + uu;
  const int aRow = grp * 16 + ln;
  const u32 stOff = (u32)(grp * 4096 + gs * 256 + urow * 16 + uu);

  float c0 = 0.f, c1 = 0.f;
  float mS = -3e38f, lS = 0.f, ctxA = 0.f;

  v8s xh_c, xl_c;
  ld8split(x, ((size_t)aRow * 512) * 32 + lq * 8, isbf, xh_c, xl_c);
  v8s a0r[8];

  // t: L0 -> h0[t]; L1 -> h1[t-1]; attn+ctx consume h1[t-2]
#pragma unroll 1
  for (int t = 0; t < 514; ++t) {
    const int rB = (t + 1) & 1, wB = t & 1;
    const u32 tag = (u32)(u16)t;
    // ---- S1: hybrid-poll h0[t-1] (t=0: zeros tag 0)
    if (t <= 512)
      poll_unpack(h0s, H0f + (size_t)rB * 65536 + grp * 4096,
                  H0m + (size_t)rB * 65536 + grp * 4096, tid, tag);
    __syncthreads();                                   // b1: h0s ready

    // ---- P1: L0 gate MFMAs
    if (t <= 512) {
#pragma unroll
      for (int kt = 0; kt < 8; ++kt)
        a0r[kt] = *(const v8s*)(h0s + ln * 264 + kt * 32 + lq * 8);
    }
    if (t < 512) {
      v4f acc0 = {0, 0, 0, 0};
      acc0 = MFMA(xh_c, W0F[0], acc0);
      if (!isbf) acc0 = MFMA(xl_c, W0F[0], acc0);
#pragma unroll
      for (int kt = 0; kt < 8; ++kt) acc0 = MFMA(a0r[kt], W0F[kt + 1], acc0);
#pragma unroll
      for (int r = 0; r < 4; ++r) gb0[(lq * 4 + r) * 64 + ln * 4 + wv] = acc0[r];
    }
    __syncthreads();                                   // b2: gb0 ready

    // ---- P2: cell0 + dual-store h0[t]; then hybrid-poll h1[t-2]
    const u32 tagS = (u32)(u16)(t + 1) << 16;
    if (t < 512) {
      const float* g0 = gb0 + (urow * 16 + uu) * 4;
      float gi = g0[0] + bg0[0], gf = g0[1] + bg0[1], gg = g0[2] + bg0[2], go = g0[3] + bg0[3];
      c0 = sigf(gf) * c0 + sigf(gi) * tanhfast(gg);
      float h = sigf(go) * tanhfast(c0);
      u32 w = (u32)f2bf(h) | tagS;
      H0f[(size_t)wB * 65536 + stOff] = w;             // fast (local L2)
      astore32(H0m + (size_t)wB * 65536 + stOff, w);   // mirror (LLC)
    }
    poll_unpack(h1s, H1f + (size_t)wB * 65536 + grp * 4096,
                H1m + (size_t)wB * 65536 + grp * 4096, tid, tag);
    __syncthreads();                                   // b3: h1s ready

    // ---- P3: L1 + attention MFMAs
    v4f acc1 = {0, 0, 0, 0}, accA0 = {0, 0, 0, 0}, accA1 = {0, 0, 0, 0};
#pragma unroll
    for (int kt = 0; kt < 8; ++kt) {
      v8s a1 = *(const v8s*)(h1s + ln * 264 + kt * 32 + lq * 8);
      acc1 = MFMA(a0r[kt], W1F[kt + 8], acc1);
      acc1 = MFMA(a1, W1F[kt], acc1);
      accA0 = MFMA(a1, AWF[kt * 2], accA0);
      accA1 = MFMA(a1, AWF[kt * 2 + 1], accA1);
    }
#pragma unroll
    for (int r = 0; r < 4; ++r) {
      gb1[(lq * 4 + r) * 64 + ln * 4 + wv] = acc1[r];
      eP[(lq * 4 + r) * 132 + (2 * wv) * 16 + ln] = accA0[r];
      eP[(lq * 4 + r) * 132 + (2 * wv + 1) * 16 + ln] = accA1[r];
    }
    // x prefetch for t+1 (off the critical path)
    v8s xh_n, xl_n;
    {
      int tn = (t + 1 < 512) ? t + 1 : 511;
      ld8split(x, ((size_t)aRow * 512 + tn) * 32 + lq * 8, isbf, xh_n, xl_n);
    }
    __syncthreads();                                   // b4: gb1/eP ready

    // ---- P4: cell1 + dual-store h1[t-1]; attention tail (h1s stable until next b2)
    if (t >= 1 && t < 513) {
      const float* g1 = gb1 + (urow * 16 + uu) * 4;
      float gi = g1[0] + bg1[0], gf = g1[1] + bg1[1], gg = g1[2] + bg1[2], go = g1[3] + bg1[3];
      c1 = sigf(gf) * c1 + sigf(gi) * tanhfast(gg);
      float h = sigf(go) * tanhfast(c1);
      u32 w = (u32)f2bf(h) | tagS;
      H1f[(size_t)rB * 65536 + stOff] = w;
      astore32(H1m + (size_t)rB * 65536 + stOff, w);
    } else if (t == 0) {
      H1f[(size_t)rB * 65536 + stOff] = tagS;          // h1[-1]=0, tag 1
      astore32(H1m + (size_t)rB * 65536 + stOff, tagS);
    }
    if (t >= 2) {
      float h1v = bf2f(h1s[urow * 264 + gUnit]);
      float e = 0.f;
#pragma unroll
      for (int j = 0; j < 8; ++j)
        e += tanhfast(eP[urow * 132 + uu + 16 * j]) * aVr[j];
      e += __shfl_xor(e, 1);
      e += __shfl_xor(e, 2);
      e += __shfl_xor(e, 4);
      e += __shfl_xor(e, 8);
      float nm = fmaxf(mS, e);
      float al = __expf(mS - nm), p = __expf(e - nm);
      lS = lS * al + p;
      ctxA = ctxA * al + p * h1v;
      mS = nm;
    }
    xh_c = xh_n; xl_c = xl_n;
  }
  ctx[(size_t)gRowU * 256 + gUnit] = ctxA / lS;
}

// ---------------- Decoder: 24 steps x 2 sub-steps + projection (hi/lo, tagged u64) -
__global__ __launch_bounds__(256, 1) void dec_kernel(
    const void* __restrict__ x,
    const void* __restrict__ dWih0, const void* __restrict__ dWhh0, const void* __restrict__ db0,
    const void* __restrict__ dWih1, const void* __restrict__ dWhh1, const void* __restrict__ db1,
    const void* __restrict__ qW, const void* __restrict__ qb,
    const float* __restrict__ ctx,
    u64* __restrict__ H0d, u64* __restrict__ H1d, u64* __restrict__ dinpG,
    void* __restrict__ out, const int* __restrict__ flagp) {
  __shared__ u16 sAhi[16 * 264], sAlo[16 * 264], sBhi[16 * 264], sBlo[16 * 264];
  __shared__ float gb[16 * 64];
  __shared__ float dinpS[16];

  const int isbf = *flagp;
  const int tid = threadIdx.x, blk = blockIdx.x;
  const int grp = blk & 15, gs = blk >> 4;
  const int lane = tid & 63, wv = tid >> 6;
  const int ln = lane & 15, lq = lane >> 4;

  v8s W0F[8], W1F[16];
  {
    const int gw = wv * 256 + gs * 16 + ln;
    const int kq = lq * 8;
#pragma unroll
    for (int kt = 0; kt < 8; ++kt) {
      W0F[kt]     = ld8hi(dWhh0, (size_t)gw * 256 + kt * 32 + kq, isbf);
      W1F[kt]     = ld8hi(dWhh1, (size_t)gw * 256 + kt * 32 + kq, isbf);
      W1F[kt + 8] = ld8hi(dWih1, (size_t)gw * 256 + kt * 32 + kq, isbf);
    }
  }
  const int urow = tid >> 4, uu = tid & 15;
  float bg0[4], bg1[4], w0v[4];
#pragma unroll
  for (int g = 0; g < 4; ++g) {
    bg0[g] = ldIn(db0, g * 256 + gs * 16 + uu, isbf);
    bg1[g] = ldIn(db1, g * 256 + gs * 16 + uu, isbf);
    w0v[g] = ldIn(dWih0, g * 256 + gs * 16 + uu, isbf);
  }
  const int gRowU = grp * 16 + urow;
  const int gUnit = gs * 16 + uu;

  float c0 = ctx[(size_t)gRowU * 256 + gUnit];
  float c1 = c0;

#pragma unroll 1
  for (int t = 0; t < 24; ++t) {
    const int pPrev = (t + 1) & 1, pCur = t & 1;
    // ---- sub-step A: layer-0 cell ----
    if (t == 0) {
      stage_f32(sAhi, sAlo, ctx + (size_t)grp * 16 * 256, tid);
      if (tid < 16)
        dinpS[tid] = ldIn(x, ((size_t)(grp * 16 + tid) * 512 + 511) * 32 + 31, isbf);
    } else {
      stage_dec(sAhi, sAlo, H0d + (size_t)pPrev * 65536 + grp * 4096, tid, (u32)(2 * t - 1));
      if (tid < 16) {
        u64 w;
        do { w = aload64(dinpG + pPrev * 256 + grp * 16 + tid); } while ((u32)(w >> 32) != (u32)(2 * t));
        dinpS[tid] = __uint_as_float((u32)w);
      }
    }
    __syncthreads();
    v4f acc = {0, 0, 0, 0};
#pragma unroll
    for (int kt = 0; kt < 8; ++kt) {
      const int off = ln * 264 + kt * 32 + lq * 8;
      acc = MFMA(*(const v8s*)(sAhi + off), W0F[kt], acc);
      acc = MFMA(*(const v8s*)(sAlo + off), W0F[kt], acc);
    }
    {
      const int bR = lq * 4;
#pragma unroll
      for (int r = 0; r < 4; ++r) gb[(bR + r) * 64 + ln * 4 + wv] = acc[r];
    }
    float di = dinpS[urow];   // hoisted: dinpS not read after sync
    __syncthreads();
    {
      const float* g0 = gb + (urow * 16 + uu) * 4;
      float gi = g0[0] + bg0[0] + di * w0v[0];
      float gf = g0[1] + bg0[1] + di * w0v[1];
      float gg = g0[2] + bg0[2] + di * w0v[2];
      float go = g0[3] + bg0[3] + di * w0v[3];
      c0 = sigf(gf) * c0 + sigf(gi) * tanhfast(gg);
      float h = sigf(go) * tanhfast(c0);
      u16 hh = f2bf(h); u16 hl = f2bf(h - bf2f(hh));
      astore64(H0d + (size_t)pCur * 65536 + gRowU * 256 + gUnit,
               (u64)hh | ((u64)hl << 16) | ((u64)(u32)(2 * t + 1) << 32));
    }
    // ---- sub-step B: layer-1 cell ----
    if (t == 0) stage_f32(sBhi, sBlo, ctx + (size_t)grp * 16 * 256, tid);
    else stage_dec(sBhi, sBlo, H1d + (size_t)pPrev * 65536 + grp * 4096, tid, (u32)(2 * t));
    stage_dec(sAhi, sAlo, H0d + (size_t)pCur * 65536 + grp * 4096, tid, (u32)(2 * t + 1));
    __syncthreads();
    v4f a1 = {0, 0, 0, 0};
#pragma unroll
    for (int kt = 0; kt < 8; ++kt) {
      const int off = ln * 264 + kt * 32 + lq * 8;
      a1 = MFMA(*(const v8s*)(sBhi + off), W1F[kt], a1);
      a1 = MFMA(*(const v8s*)(sBlo + off), W1F[kt], a1);
      a1 = MFMA(*(const v8s*)(sAhi + off), W1F[kt + 8], a1);
      a1 = MFMA(*(const v8s*)(sAlo + off), W1F[kt + 8], a1);
    }
    {
      const int bR = lq * 4;
#pragma unroll
      for (int r = 0; r < 4; ++r) gb[(bR + r) * 64 + ln * 4 + wv] = a1[r];
    }
    __syncthreads();
    {
      const float* g1 = gb + (urow * 16 + uu) * 4;
      float gi = g1[0] + bg1[0], gf = g1[1] + bg1[1], gg = g1[2] + bg1[2], go = g1[3] + bg1[3];
      c1 = sigf(gf) * c1 + sigf(gi) * tanhfast(gg);
      float h = sigf(go) * tanhfast(c1);
      u16 hh = f2bf(h); u16 hl = f2bf(h - bf2f(hh));
      astore64(H1d + (size_t)pCur * 65536 + gRowU * 256 + gUnit,
               (u64)hh | ((u64)hl << 16) | ((u64)(u32)(2 * t + 2) << 32));
      if (gUnit == 0)
        astore64(dinpG + pCur * 256 + gRowU,
                 (u64)__float_as_uint(h) | ((u64)(u32)(2 * t + 2) << 32));
    }
  }
  // projection: stage h1d[23] (parity 1, tag 48) into LDS, then compute
  stage_dec(sAhi, sAlo, H1d + (size_t)65536 + grp * 4096, tid, 48u);
  __syncthreads();
  if (gs < 12 && tid < 96) {
    int r = tid / 6, p = tid % 6;
    int qo = gs * 6 + p, row = grp * 16 + r;
    float s = ldIn(qb, qo, isbf);
    for (int h = 0; h < 256; ++h)
      s += (bf2f(sAhi[r * 264 + h]) + bf2f(sAlo[r * 264 + h])) * ldIn(qW, (size_t)qo * 256 + h, isbf);
    if (isbf) ((u16*)out)[row * 72 + qo] = f2bf(s);
    else      ((float*)out)[row * 72 + qo] = s;
  }
}

extern "C" void kernel_launch(void* const* d_in, const int* in_sizes, int n_in,
                              void* d_out, int out_size, void* d_ws, size_t ws_size,
                              hipStream_t stream) {
  const void* x     = d_in[0];
  const void* eWih0 = d_in[1];
  const void* eWhh0 = d_in[2];
  const void* eb0   = d_in[3];
  const void* eWih1 = d_in[4];
  const void* eWhh1 = d_in[5];
  const void* eb1   = d_in[6];
  const void* dWih0 = d_in[7];
  const void* dWhh0 = d_in[8];
  const void* db0   = d_in[9];
  const void* dWih1 = d_in[10];
  const void* dWhh1 = d_in[11];
  const void* db1   = d_in[12];
  const void* aW    = d_in[13];
  const void* aV    = d_in[14];
  const void* qW    = d_in[15];
  const void* qb    = d_in[16];

  char* wsb = (char*)d_ws;
  // enc exchange buffers (live during enc only):
  u32*   H0f   = (u32*)(wsb + 0);              // [2][grp16][gs16][row16][16] u32 = 524288
  u32*   H1f   = (u32*)(wsb + 524288);         // -> 1048576
  u32*   H0m   = (u32*)(wsb + 1048576);        // -> 1572864
  u32*   H1m   = (u32*)(wsb + 1572864);        // -> 2097152
  int*   flag  = (int*)(wsb + 2097152);        // 256 -> 2097408
  float* ctx   = (float*)(wsb + 2097408);      // 262144 -> 2359552
  u64*   dinpG = (u64*)(wsb + 2359552);        // [2][256] u64 = 4096 -> 2363648
  // dec buffers OVERLAY enc exchange region (disjoint lifetimes). enc residue
  // words have bit31 of the u64 high-u32 clear with value 0 or >=65536; dec
  // expects exact small tags 1..48 -> never falsely validates. Whole ws is
  // memset to 0 every launch (kills cross-launch tag reuse).
  u64*   H0d   = (u64*)(wsb + 0);              // [2][256][256] u64 = 1048576
  u64*   H1d   = (u64*)(wsb + 1048576);        // -> 2097152
  // total ws: 2,363,648 bytes

  hipMemsetAsync(wsb, 0, 2363648, stream);

  sniff_kernel<<<1, 256, 0, stream>>>((const u16*)eWhh0, flag);
  enc_kernel<<<256, 256, 0, stream>>>(x, eWih0, eWhh0, eb0, eWih1, eWhh1, eb1,
                                      aW, aV, H0f, H1f, H0m, H1m, ctx, flag);
  dec_kernel<<<256, 256, 0, stream>>>(x, dWih0, dWhh0, db0, dWih1, dWhh1, db1,
                                      qW, qb, ctx, H0d, H1d, dinpG,
                                      d_out, flag);
}